// Round 12
// baseline (78.621 us; speedup 1.0000x reference)
//
#include <hip/hip_runtime.h>
#include <hip/hip_bf16.h>

#define NTOK 4096
#define BATCH 8
#define NROWS (BATCH * NTOK)   // 32768

typedef __attribute__((ext_vector_type(8))) _Float16 hfx8;
typedef __attribute__((ext_vector_type(8))) short sx8;
typedef sx8 sx8a __attribute__((may_alias));   // LDS loads: alias-everything type
typedef __attribute__((ext_vector_type(4))) short bfx4;
typedef __attribute__((ext_vector_type(4))) float f32x4;

// float -> f16 bits (RTE via _Float16 cast)
__device__ __forceinline__ short f2h(float f) {
    _Float16 h = (_Float16)f;
    return __builtin_bit_cast(short, h);
}
__device__ __forceinline__ unsigned pk2h(float a, float b) {
    return (unsigned)(unsigned short)f2h(a) | ((unsigned)(unsigned short)f2h(b) << 16);
}
// ordered LDS 16B load: may_alias (TBAA sees RAW vs short/unsigned stores) -> f16 vec
__device__ __forceinline__ hfx8 ldsld(const short* p) {
    return __builtin_bit_cast(hfx8, *reinterpret_cast<const sx8a*>(p));
}

// XOR swizzle for the shared A[64][256] tile (8-short granular, bijective per row)
__device__ __forceinline__ int aswz(int row, int col) {
    return (row * 256 + col) ^ ((row & 7) << 3);
}
// unit-rotation swizzle for per-wave xo[64][32] slots: 2-way-free column reads
__device__ __forceinline__ int xoidx(int row, int col) {
    return row * 32 + ((((col >> 3) + (row >> 1)) & 3) << 3) + (col & 7);
}

#define MFMA16(a, b, c) __builtin_amdgcn_mfma_f32_16x16x32_f16(a, b, c, 0, 0, 0)
// zero-cost compiler-only memory barrier: orders LDS stage write/read groups at
// IR level without draining counters or pinning the machine scheduler
#define CBAR() asm volatile("" ::: "memory")

// ---------------- weight prep: WT[co][ci] = f16(scale * g[ci] * W[ci][co]) ----------------
__global__ __launch_bounds__(256) void prep_w(
    const float* __restrict__ Wq, const float* __restrict__ Wk,
    const float* __restrict__ Wv, const float* __restrict__ Wp,
    const float* __restrict__ qg, const float* __restrict__ qb,
    const float* __restrict__ kg, const float* __restrict__ kb,
    const float* __restrict__ vg, const float* __restrict__ vb,
    short* __restrict__ wt, float* __restrict__ bbp) {
    int m = blockIdx.x;
    int ci0 = blockIdx.y * 16;
    const float *W, *g, *be;
    float scale = 1.0f;
    if (m == 0)      { W = Wq; g = qg; be = qb; scale = 0.17677669529663687f; }
    else if (m == 1) { W = Wk; g = kg; be = kb; }
    else if (m == 2) { W = Wv; g = vg; be = vb; }
    else             { W = Wp; g = nullptr; be = nullptr; }
    __shared__ float tile[16][257];
    int t = threadIdx.x;
#pragma unroll
    for (int i = 0; i < 16; i++)
        tile[i][t] = W[(size_t)(ci0 + i) * 256 + t];
    __syncthreads();
    float p = 0.f;
    if (be) {
#pragma unroll
        for (int i = 0; i < 16; i++) p += be[ci0 + i] * tile[i][t];
    }
    bbp[(m * 16 + blockIdx.y) * 256 + t] = p;
    short* WT = wt + m * 65536 + t * 256 + ci0;
    short o0[8], o1[8];
#pragma unroll
    for (int j = 0; j < 8; j++) {
        float gv = g ? g[ci0 + j] : 1.0f;
        o0[j] = f2h(scale * gv * tile[j][t]);
    }
#pragma unroll
    for (int j = 0; j < 8; j++) {
        float gv = g ? g[ci0 + 8 + j] : 1.0f;
        o1[j] = f2h(scale * gv * tile[8 + j][t]);
    }
#pragma unroll
    for (int j = 0; j < 8; j++) { WT[j] = o0[j]; WT[8 + j] = o1[j]; }
}

__global__ __launch_bounds__(256) void prep_b(
    const float* __restrict__ bq, const float* __restrict__ bk,
    const float* __restrict__ bv, const float* __restrict__ bp,
    const float* __restrict__ bbp, float* __restrict__ bb) {
    int m = blockIdx.x, t = threadIdx.x;
    const float* bias = (m == 0) ? bq : (m == 1) ? bk : (m == 2) ? bv : bp;
    float scale = (m == 0) ? 0.17677669529663687f : 1.0f;
    float s = bias[t];
#pragma unroll
    for (int i = 0; i < 16; i++) s += bbp[(m * 16 + i) * 256 + t];
    bb[m * 256 + t] = scale * s;
}

// ---------------- mega kernel: LN + qkv GEMM + attention + projection ----------------
// 512 blocks (b, chunk) x 512 threads (8 waves; wave = head = 32-col strip).
// All staged tensors f16; accum fp32. No waitcnt-drain fences: LDS loads use a
// may_alias type so the compiler SEES every scratch RAW/WAR edge and emits
// minimal counted lgkmcnt waits; CBAR() adds zero-cost IR-level ordering.
// A (swizzled [64][256]): cva_hat, then per-wave transpose scratch (A + w*2048,
//   all staging uses pitch-40 32-row passes -> max index 1271 < 2048).
// xo[8][2048] per-wave slots (rot-swizzled [64][32]): xs_hat, then o_s.
__global__ __launch_bounds__(512, 4) void mega(const float* __restrict__ x,
                                               const float* __restrict__ cva,
                                               const short* __restrict__ wt,
                                               const float* __restrict__ bb,
                                               float* __restrict__ out) {
    int id = blockIdx.x;
    int b = id >> 6, ch = id & 63;
    int t = threadIdx.x, w = t >> 6, l = t & 63, c = l & 15, g = l >> 4;

    __shared__ short A[64 * 256];       // 32768 B
    __shared__ short xo[8][2048];       // 32768 B
    __shared__ float red[8][64][2];     // 4096 B
    short* S = A + w * 2048;            // per-wave scratch, valid AFTER bar1

    const float* xb   = x + (size_t)b * 1048576 + ch * 64;
    const float* cvab = cva + (size_t)(b * 4096 + ch * 64) * 256;

    // ph0: cva loads -> LN -> A;  x loads -> stats partials -> red
    {
        int r16 = g;  // row within pass-quad (16 lanes per row)
        float fv[2][16];
#pragma unroll
        for (int p2 = 0; p2 < 2; p2++) {
            int row = w * 8 + p2 * 4 + r16;
#pragma unroll
            for (int i = 0; i < 4; i++) {
                float4 v4 = *reinterpret_cast<const float4*>(
                    cvab + (size_t)row * 256 + c * 16 + i * 4);
                fv[p2][i * 4 + 0] = v4.x;
                fv[p2][i * 4 + 1] = v4.y;
                fv[p2][i * 4 + 2] = v4.z;
                fv[p2][i * 4 + 3] = v4.w;
            }
        }
        // issue x column loads early (latency hidden under LN compute)
        float xg[32];
#pragma unroll
        for (int i = 0; i < 32; i++) xg[i] = xb[(size_t)(w * 32 + i) * 4096 + l];

#pragma unroll
        for (int p2 = 0; p2 < 2; p2++) {
            int row = w * 8 + p2 * 4 + r16;
            float s = 0.f, q2 = 0.f;
#pragma unroll
            for (int i = 0; i < 16; i++) {
                s += fv[p2][i];
                q2 += fv[p2][i] * fv[p2][i];
            }
            s += __shfl_xor(s, 1);  q2 += __shfl_xor(q2, 1);
            s += __shfl_xor(s, 2);  q2 += __shfl_xor(q2, 2);
            s += __shfl_xor(s, 4);  q2 += __shfl_xor(q2, 4);
            s += __shfl_xor(s, 8);  q2 += __shfl_xor(q2, 8);
            float mean = s * (1.0f / 256.0f);
            float rstd = rsqrtf(q2 * (1.0f / 256.0f) - mean * mean + 1e-5f);
            short o0[8], o1[8];
#pragma unroll
            for (int jj = 0; jj < 8; jj++) {
                o0[jj] = f2h((fv[p2][jj] - mean) * rstd);
                o1[jj] = f2h((fv[p2][8 + jj] - mean) * rstd);
            }
            short* d0 = A + aswz(row, c * 16);
            short* d1 = A + aswz(row, c * 16 + 8);
#pragma unroll
            for (int jj = 0; jj < 8; jj++) { d0[jj] = o0[jj]; d1[jj] = o1[jj]; }
        }

        // x stats partials (token = l, c-slice = w*32..+32)
        float s = 0.f, q2 = 0.f;
#pragma unroll
        for (int i = 0; i < 32; i++) { s += xg[i]; q2 += xg[i] * xg[i]; }
        red[w][l][0] = s;
        red[w][l][1] = q2;
        __syncthreads();  // bar0: cva_hat ready, red ready

        // xs_hat -> xo[w] (rot-swizzled [64][32])
        float s2 = 0.f, q22 = 0.f;
#pragma unroll
        for (int j2 = 0; j2 < 8; j2++) { s2 += red[j2][l][0]; q22 += red[j2][l][1]; }
        float xmean = s2 * (1.0f / 256.0f);
        float xrstd = rsqrtf(q22 * (1.0f / 256.0f) - xmean * xmean + 1e-5f);
#pragma unroll
        for (int i2 = 0; i2 < 4; i2++) {
            short* dd = xo[w] + xoidx(l, i2 * 8);
#pragma unroll
            for (int jj = 0; jj < 8; jj++) dd[jj] = f2h((xg[i2 * 8 + jj] - xmean) * xrstd);
        }
    }

    // ph1: merged q+k GEMM from A (cva_hat), weights streamed from L2
    f32x4 qa[4][2] = {}, ka[4][2] = {};
    {
        const short* wq0 = wt + (size_t)(w * 32 + c) * 256 + g * 8;
        const short* wq1 = wq0 + 16 * 256;
        const short* wk0 = wq0 + 65536;
        const short* wk1 = wq1 + 65536;
#pragma unroll
        for (int ks = 0; ks < 8; ks++) {
            hfx8 af[4];
#pragma unroll
            for (int m = 0; m < 4; m++)
                af[m] = ldsld(A + aswz(m * 16 + c, ks * 32 + g * 8));
            hfx8 q0 = *reinterpret_cast<const hfx8*>(wq0 + ks * 32);
            hfx8 q1 = *reinterpret_cast<const hfx8*>(wq1 + ks * 32);
            hfx8 k0 = *reinterpret_cast<const hfx8*>(wk0 + ks * 32);
            hfx8 k1 = *reinterpret_cast<const hfx8*>(wk1 + ks * 32);
#pragma unroll
            for (int m = 0; m < 4; m++) {
                qa[m][0] = MFMA16(af[m], q0, qa[m][0]);
                qa[m][1] = MFMA16(af[m], q1, qa[m][1]);
                ka[m][0] = MFMA16(af[m], k0, ka[m][0]);
                ka[m][1] = MFMA16(af[m], k1, ka[m][1]);
            }
        }
    }
    __syncthreads();  // bar1: all cva_hat reads done -> A becomes scratch; xs_hat ready

    // ---- barrier-free middle span (wave-private scratch; may_alias ordering) ----

    // q^T via A-slice scratch, two 32-token passes [32][40]
    hfx8 qf[4];
    {
        float b0 = bb[w * 32 + c], b1 = bb[w * 32 + 16 + c];
#pragma unroll
        for (int th = 0; th < 2; th++) {
#pragma unroll
            for (int m2 = 0; m2 < 2; m2++)
#pragma unroll
                for (int j = 0; j < 4; j++) {
                    S[(m2 * 16 + g * 4 + j) * 40 + c]      = f2h(qa[th * 2 + m2][0][j] + b0);
                    S[(m2 * 16 + g * 4 + j) * 40 + 16 + c] = f2h(qa[th * 2 + m2][1][j] + b1);
                }
            CBAR();
#pragma unroll
            for (int np = 0; np < 2; np++)
                qf[th * 2 + np] = ldsld(S + (np * 16 + c) * 40 + g * 8);
            CBAR();
        }
    }

    // k^T
    hfx8 kf[4];
    {
        float b0 = bb[256 + w * 32 + c], b1 = bb[256 + w * 32 + 16 + c];
#pragma unroll
        for (int th = 0; th < 2; th++) {
#pragma unroll
            for (int m2 = 0; m2 < 2; m2++)
#pragma unroll
                for (int j = 0; j < 4; j++) {
                    S[(m2 * 16 + g * 4 + j) * 40 + c]      = f2h(ka[th * 2 + m2][0][j] + b0);
                    S[(m2 * 16 + g * 4 + j) * 40 + 16 + c] = f2h(ka[th * 2 + m2][1][j] + b1);
                }
            CBAR();
#pragma unroll
            for (int np = 0; np < 2; np++)
                kf[th * 2 + np] = ldsld(S + (np * 16 + c) * 40 + g * 8);
            CBAR();
        }
    }

    // QK^T in S^T orientation: sa[m][np] = S^T[key 16m+4g+j][token 16np+c]
    f32x4 sa[4][4] = {};
#pragma unroll
    for (int m = 0; m < 4; m++)
#pragma unroll
        for (int np = 0; np < 4; np++)
            sa[m][np] = MFMA16(kf[m], qf[np], sa[m][np]);

    // softmax over keys (rows of S^T)
    float rs[4];
#pragma unroll
    for (int np = 0; np < 4; np++) {
        float mx = sa[0][np][0];
#pragma unroll
        for (int m = 0; m < 4; m++)
#pragma unroll
            for (int j = 0; j < 4; j++) mx = fmaxf(mx, sa[m][np][j]);
        mx = fmaxf(mx, __shfl_xor(mx, 16));
        mx = fmaxf(mx, __shfl_xor(mx, 32));
        float sum = 0.f;
#pragma unroll
        for (int m = 0; m < 4; m++)
#pragma unroll
            for (int j = 0; j < 4; j++) {
                float e = __expf(sa[m][np][j] - mx);
                sa[m][np][j] = e;
                sum += e;
            }
        sum += __shfl_xor(sum, 16);
        sum += __shfl_xor(sum, 32);
        rs[np] = 1.0f / sum;
    }

    // pack P^T to f16 pairs in registers
    unsigned Pp[4][4][2];
#pragma unroll
    for (int m = 0; m < 4; m++)
#pragma unroll
        for (int np = 0; np < 4; np++) {
            Pp[m][np][0] = pk2h(sa[m][np][0], sa[m][np][1]);
            Pp[m][np][1] = pk2h(sa[m][np][2], sa[m][np][3]);
        }

    // vGEMM from xo (xs_hat slots of all waves, rot-swizzled, 2-way-free)
    f32x4 va[4][2] = {};
    {
        const short* w0 = wt + 2 * 65536 + (size_t)(w * 32 + c) * 256 + g * 8;
        const short* w1 = w0 + 16 * 256;
#pragma unroll
        for (int ks = 0; ks < 8; ks++) {
            hfx8 af[4];
#pragma unroll
            for (int m = 0; m < 4; m++)
                af[m] = ldsld(xo[ks] + xoidx(m * 16 + c, g * 8));
            hfx8 v0 = *reinterpret_cast<const hfx8*>(w0 + ks * 32);
            hfx8 v1 = *reinterpret_cast<const hfx8*>(w1 + ks * 32);
#pragma unroll
            for (int m = 0; m < 4; m++) {
                va[m][0] = MFMA16(af[m], v0, va[m][0]);
                va[m][1] = MFMA16(af[m], v1, va[m][1]);
            }
        }
    }

    // V^T through A-slice scratch in TWO key-half passes [32 d][32 keys] pitch 40
    hfx8 vf[2][2];
    {
        float b0 = bb[512 + w * 32 + c], b1 = bb[512 + w * 32 + 16 + c];
#pragma unroll
        for (int ks = 0; ks < 2; ks++) {
#pragma unroll
            for (int m2 = 0; m2 < 2; m2++) {
                int m = ks * 2 + m2;
                bfx4 t0, t1;
#pragma unroll
                for (int j = 0; j < 4; j++) {
                    t0[j] = f2h(va[m][0][j] + b0);
                    t1[j] = f2h(va[m][1][j] + b1);
                }
                *reinterpret_cast<bfx4*>(S + c * 40 + m2 * 16 + g * 4)        = t0;
                *reinterpret_cast<bfx4*>(S + (16 + c) * 40 + m2 * 16 + g * 4) = t1;
            }
            CBAR();
#pragma unroll
            for (int mD = 0; mD < 2; mD++)
                vf[ks][mD] = ldsld(S + (mD * 16 + c) * 40 + g * 8);
            CBAR();
        }
    }

    // PV: O^T accumulate; P^T through A-slice [32][40] in 4 rounds (key-half x token-half)
    f32x4 oa[2][4] = {};
#pragma unroll
    for (int ks = 0; ks < 2; ks++) {
#pragma unroll
        for (int th = 0; th < 2; th++) {
#pragma unroll
            for (int m2 = 0; m2 < 2; m2++)
#pragma unroll
                for (int np = 0; np < 2; np++) {
                    *reinterpret_cast<unsigned*>(S + (np * 16 + c) * 40 + m2 * 16 + g * 4)     = Pp[ks * 2 + m2][th * 2 + np][0];
                    *reinterpret_cast<unsigned*>(S + (np * 16 + c) * 40 + m2 * 16 + g * 4 + 2) = Pp[ks * 2 + m2][th * 2 + np][1];
                }
            CBAR();
            hfx8 pf[2];
#pragma unroll
            for (int np = 0; np < 2; np++)
                pf[np] = ldsld(S + (np * 16 + c) * 40 + g * 8);
            CBAR();
#pragma unroll
            for (int mD = 0; mD < 2; mD++)
#pragma unroll
                for (int np = 0; np < 2; np++)
                    oa[mD][th * 2 + np] = MFMA16(vf[ks][mD], pf[np], oa[mD][th * 2 + np]);
        }
    }
    __syncthreads();  // bar2: all xs_hat reads (vGEMM) done -> xo reusable as o_s

    // o_s (normalized) -> xo[w]
#pragma unroll
    for (int mD = 0; mD < 2; mD++)
#pragma unroll
        for (int np = 0; np < 4; np++) {
            bfx4 o4;
#pragma unroll
            for (int j = 0; j < 4; j++) o4[j] = f2h(oa[mD][np][j] * rs[np]);
            *reinterpret_cast<bfx4*>(xo[w] + xoidx(np * 16 + c, mD * 16 + g * 4)) = o4;
        }
    __syncthreads();  // bar3: o_s ready

    // proj (wave = 32 output channels) + direct C-layout fp32 stores
    {
        f32x4 pa[4][2] = {};
        const short* w0 = wt + 3 * 65536 + (size_t)(w * 32 + c) * 256 + g * 8;
        const short* w1 = w0 + 16 * 256;
#pragma unroll
        for (int ks = 0; ks < 8; ks++) {
            hfx8 af[4];
#pragma unroll
            for (int m = 0; m < 4; m++)
                af[m] = ldsld(xo[ks] + xoidx(m * 16 + c, g * 8));
            hfx8 p0 = *reinterpret_cast<const hfx8*>(w0 + ks * 32);
            hfx8 p1 = *reinterpret_cast<const hfx8*>(w1 + ks * 32);
#pragma unroll
            for (int m = 0; m < 4; m++) {
                pa[m][0] = MFMA16(af[m], p0, pa[m][0]);
                pa[m][1] = MFMA16(af[m], p1, pa[m][1]);
            }
        }
        float* outb = out + (size_t)b * 1048576 + ch * 64;
#pragma unroll
        for (int p = 0; p < 2; p++) {
            int co = w * 32 + p * 16 + c;
            float bvv = bb[768 + co];
            float* op = outb + (size_t)co * 4096 + g * 4;
#pragma unroll
            for (int m = 0; m < 4; m++) {
                float4 st;
                st.x = pa[m][p][0] + bvv;
                st.y = pa[m][p][1] + bvv;
                st.z = pa[m][p][2] + bvv;
                st.w = pa[m][p][3] + bvv;
                *reinterpret_cast<float4*>(op + m * 16) = st;
            }
        }
    }
}

extern "C" void kernel_launch(void* const* d_in, const int* in_sizes, int n_in,
                              void* d_out, int out_size, void* d_ws, size_t ws_size,
                              hipStream_t stream) {
    const float* x   = (const float*)d_in[0];
    const float* cva = (const float*)d_in[1];
    const float* qg  = (const float*)d_in[2];
    const float* qb  = (const float*)d_in[3];
    const float* kg  = (const float*)d_in[4];
    const float* kb  = (const float*)d_in[5];
    const float* vg  = (const float*)d_in[6];
    const float* vb  = (const float*)d_in[7];
    const float* Wq  = (const float*)d_in[8];
    const float* bq  = (const float*)d_in[9];
    const float* Wk  = (const float*)d_in[10];
    const float* bk  = (const float*)d_in[11];
    const float* Wv  = (const float*)d_in[12];
    const float* bv  = (const float*)d_in[13];
    const float* Wp  = (const float*)d_in[14];
    const float* bp  = (const float*)d_in[15];
    float* out = (float*)d_out;
    char* ws = (char*)d_ws;

    short* wt  = (short*)(ws);
    float* bb  = (float*)(ws + 4 * 65536 * sizeof(short));
    float* bbp = bb + 1024;

    prep_w<<<dim3(4, 16), 256, 0, stream>>>(Wq, Wk, Wv, Wp, qg, qb, kg, kb, vg, vb,
                                            wt, bbp);
    prep_b<<<4, 256, 0, stream>>>(bq, bk, bv, bp, bbp, bb);

    mega<<<512, 512, 0, stream>>>(x, cva, wt, bb, out);
}

// Round 13
// 74.946 us; speedup vs baseline: 1.0490x; 1.0490x over previous
//
#include <hip/hip_runtime.h>
#include <hip/hip_bf16.h>

#define NTOK 4096
#define BATCH 8
#define NROWS (BATCH * NTOK)   // 32768

typedef __attribute__((ext_vector_type(8))) _Float16 hfx8;
typedef __attribute__((ext_vector_type(4))) short bfx4;
typedef __attribute__((ext_vector_type(4))) float f32x4;

// float -> f16 bits (RTE via _Float16 cast)
__device__ __forceinline__ short f2h(float f) {
    _Float16 h = (_Float16)f;
    return __builtin_bit_cast(short, h);
}
__device__ __forceinline__ unsigned pk2h(float a, float b) {
    return (unsigned)(unsigned short)f2h(a) | ((unsigned)(unsigned short)f2h(b) << 16);
}

// XOR swizzle for the shared A[64][256] tile (8-short granular, bijective per row)
__device__ __forceinline__ int aswz(int row, int col) {
    return (row * 256 + col) ^ ((row & 7) << 3);
}
// unit-rotation swizzle for per-wave xo[64][32] slots: 2-way-free column reads
__device__ __forceinline__ int xoidx(int row, int col) {
    return row * 32 + ((((col >> 3) + (row >> 1)) & 3) << 3) + (col & 7);
}

#define MFMA16(a, b, c) __builtin_amdgcn_mfma_f32_16x16x32_f16(a, b, c, 0, 0, 0)
#define LGKM0()                                              \
    do {                                                     \
        asm volatile("s_waitcnt lgkmcnt(0)" ::: "memory");   \
        __builtin_amdgcn_sched_barrier(0);                   \
    } while (0)

// ---------------- weight prep: WT[co][ci] = f16(scale * g[ci] * W[ci][co]) ----------------
__global__ __launch_bounds__(256) void prep_w(
    const float* __restrict__ Wq, const float* __restrict__ Wk,
    const float* __restrict__ Wv, const float* __restrict__ Wp,
    const float* __restrict__ qg, const float* __restrict__ qb,
    const float* __restrict__ kg, const float* __restrict__ kb,
    const float* __restrict__ vg, const float* __restrict__ vb,
    short* __restrict__ wt, float* __restrict__ bbp) {
    int m = blockIdx.x;
    int ci0 = blockIdx.y * 16;
    const float *W, *g, *be;
    float scale = 1.0f;
    if (m == 0)      { W = Wq; g = qg; be = qb; scale = 0.17677669529663687f; }
    else if (m == 1) { W = Wk; g = kg; be = kb; }
    else if (m == 2) { W = Wv; g = vg; be = vb; }
    else             { W = Wp; g = nullptr; be = nullptr; }
    __shared__ float tile[16][257];
    int t = threadIdx.x;
#pragma unroll
    for (int i = 0; i < 16; i++)
        tile[i][t] = W[(size_t)(ci0 + i) * 256 + t];
    __syncthreads();
    float p = 0.f;
    if (be) {
#pragma unroll
        for (int i = 0; i < 16; i++) p += be[ci0 + i] * tile[i][t];
    }
    bbp[(m * 16 + blockIdx.y) * 256 + t] = p;
    short* WT = wt + m * 65536 + t * 256 + ci0;
    short o0[8], o1[8];
#pragma unroll
    for (int j = 0; j < 8; j++) {
        float gv = g ? g[ci0 + j] : 1.0f;
        o0[j] = f2h(scale * gv * tile[j][t]);
    }
#pragma unroll
    for (int j = 0; j < 8; j++) {
        float gv = g ? g[ci0 + 8 + j] : 1.0f;
        o1[j] = f2h(scale * gv * tile[8 + j][t]);
    }
#pragma unroll
    for (int j = 0; j < 8; j++) { WT[j] = o0[j]; WT[8 + j] = o1[j]; }
}

__global__ __launch_bounds__(256) void prep_b(
    const float* __restrict__ bq, const float* __restrict__ bk,
    const float* __restrict__ bv, const float* __restrict__ bp,
    const float* __restrict__ bbp, float* __restrict__ bb) {
    int m = blockIdx.x, t = threadIdx.x;
    const float* bias = (m == 0) ? bq : (m == 1) ? bk : (m == 2) ? bv : bp;
    float scale = (m == 0) ? 0.17677669529663687f : 1.0f;
    float s = bias[t];
#pragma unroll
    for (int i = 0; i < 16; i++) s += bbp[(m * 16 + i) * 256 + t];
    bb[m * 256 + t] = scale * s;
}

// ---------------- mega kernel: LN + qkv GEMM + attention + projection ----------------
// 512 blocks (b, chunk) x 512 threads (8 waves; wave = head = 32-col strip).
// Round-10 structure + manual cross-fence weight prefetch (qw0/vw0/pw0) and
// s_setprio around MFMA clusters. All staged tensors f16; accum fp32.
__global__ __launch_bounds__(512, 4) void mega(const float* __restrict__ x,
                                               const float* __restrict__ cva,
                                               const short* __restrict__ wt,
                                               const float* __restrict__ bb,
                                               float* __restrict__ out) {
    int id = blockIdx.x;
    int b = id >> 6, ch = id & 63;
    int t = threadIdx.x, w = t >> 6, l = t & 63, c = l & 15, g = l >> 4;

    __shared__ short A[64 * 256];       // 32768 B
    __shared__ short xo[8][2048];       // 32768 B
    __shared__ float red[8][64][2];     // 4096 B
    short* S = A + w * 2048;            // per-wave scratch, valid AFTER bar1

    const float* xb   = x + (size_t)b * 1048576 + ch * 64;
    const float* cvab = cva + (size_t)(b * 4096 + ch * 64) * 256;

    const short* wq0 = wt + (size_t)(w * 32 + c) * 256 + g * 8;
    const short* wq1 = wq0 + 16 * 256;
    const short* wk0 = wq0 + 65536;
    const short* wk1 = wq1 + 65536;
    const short* wv0 = wt + 2 * 65536 + (size_t)(w * 32 + c) * 256 + g * 8;
    const short* wv1 = wv0 + 16 * 256;
    const short* wp0 = wt + 3 * 65536 + (size_t)(w * 32 + c) * 256 + g * 8;
    const short* wp1 = wp0 + 16 * 256;

    hfx8 qw0[8];   // prefetched q-weight half-panel (issued in ph0)

    // ph0: cva loads -> LN -> A;  x loads -> stats partials -> red
    {
        int r16 = g;  // row within pass-quad (16 lanes per row)
        float fv[2][16];
#pragma unroll
        for (int p2 = 0; p2 < 2; p2++) {
            int row = w * 8 + p2 * 4 + r16;
#pragma unroll
            for (int i = 0; i < 4; i++) {
                float4 v4 = *reinterpret_cast<const float4*>(
                    cvab + (size_t)row * 256 + c * 16 + i * 4);
                fv[p2][i * 4 + 0] = v4.x;
                fv[p2][i * 4 + 1] = v4.y;
                fv[p2][i * 4 + 2] = v4.z;
                fv[p2][i * 4 + 3] = v4.w;
            }
        }
        // issue x column loads early (latency hidden under LN compute)
        float xg[32];
#pragma unroll
        for (int i = 0; i < 32; i++) xg[i] = xb[(size_t)(w * 32 + i) * 4096 + l];

#pragma unroll
        for (int p2 = 0; p2 < 2; p2++) {
            int row = w * 8 + p2 * 4 + r16;
            float s = 0.f, q2 = 0.f;
#pragma unroll
            for (int i = 0; i < 16; i++) {
                s += fv[p2][i];
                q2 += fv[p2][i] * fv[p2][i];
            }
            s += __shfl_xor(s, 1);  q2 += __shfl_xor(q2, 1);
            s += __shfl_xor(s, 2);  q2 += __shfl_xor(q2, 2);
            s += __shfl_xor(s, 4);  q2 += __shfl_xor(q2, 4);
            s += __shfl_xor(s, 8);  q2 += __shfl_xor(q2, 8);
            float mean = s * (1.0f / 256.0f);
            float rstd = rsqrtf(q2 * (1.0f / 256.0f) - mean * mean + 1e-5f);
            short o0[8], o1[8];
#pragma unroll
            for (int jj = 0; jj < 8; jj++) {
                o0[jj] = f2h((fv[p2][jj] - mean) * rstd);
                o1[jj] = f2h((fv[p2][8 + jj] - mean) * rstd);
            }
            short* d0 = A + aswz(row, c * 16);
            short* d1 = A + aswz(row, c * 16 + 8);
#pragma unroll
            for (int jj = 0; jj < 8; jj++) { d0[jj] = o0[jj]; d1[jj] = o1[jj]; }
        }

        // prefetch q half-panel now: latency hides under stats + bar0 + xs writes
#pragma unroll
        for (int ks = 0; ks < 8; ks++)
            qw0[ks] = *reinterpret_cast<const hfx8*>(wq0 + ks * 32);

        // x stats partials (token = l, c-slice = w*32..+32)
        float s = 0.f, q2 = 0.f;
#pragma unroll
        for (int i = 0; i < 32; i++) { s += xg[i]; q2 += xg[i] * xg[i]; }
        red[w][l][0] = s;
        red[w][l][1] = q2;
        __syncthreads();  // bar0: cva_hat ready, red ready

        // xs_hat -> xo[w] (rot-swizzled [64][32])
        float s2 = 0.f, q22 = 0.f;
#pragma unroll
        for (int j2 = 0; j2 < 8; j2++) { s2 += red[j2][l][0]; q22 += red[j2][l][1]; }
        float xmean = s2 * (1.0f / 256.0f);
        float xrstd = rsqrtf(q22 * (1.0f / 256.0f) - xmean * xmean + 1e-5f);
#pragma unroll
        for (int i2 = 0; i2 < 4; i2++) {
            short* dd = xo[w] + xoidx(l, i2 * 8);
#pragma unroll
            for (int jj = 0; jj < 8; jj++) dd[jj] = f2h((xg[i2 * 8 + jj] - xmean) * xrstd);
        }
    }

    // ph1: merged q+k GEMM from A (cva_hat); q half-panel prefetched
    f32x4 qa[4][2] = {}, ka[4][2] = {};
    {
        __builtin_amdgcn_s_setprio(1);
#pragma unroll
        for (int ks = 0; ks < 8; ks++) {
            hfx8 af[4];
#pragma unroll
            for (int m = 0; m < 4; m++)
                af[m] = *reinterpret_cast<const hfx8*>(A + aswz(m * 16 + c, ks * 32 + g * 8));
            hfx8 q1 = *reinterpret_cast<const hfx8*>(wq1 + ks * 32);
            hfx8 k0 = *reinterpret_cast<const hfx8*>(wk0 + ks * 32);
            hfx8 k1 = *reinterpret_cast<const hfx8*>(wk1 + ks * 32);
#pragma unroll
            for (int m = 0; m < 4; m++) {
                qa[m][0] = MFMA16(af[m], qw0[ks], qa[m][0]);
                qa[m][1] = MFMA16(af[m], q1, qa[m][1]);
                ka[m][0] = MFMA16(af[m], k0, ka[m][0]);
                ka[m][1] = MFMA16(af[m], k1, ka[m][1]);
            }
        }
        __builtin_amdgcn_s_setprio(0);
    }
    __syncthreads();  // bar1: all cva_hat reads done -> A becomes scratch; xs_hat ready

    // prefetch v half-panel: latency hides under q^T/k^T/QK/softmax
    hfx8 vw0[8];
#pragma unroll
    for (int ks = 0; ks < 8; ks++)
        vw0[ks] = *reinterpret_cast<const hfx8*>(wv0 + ks * 32);

    // ---- barrier-free middle span (all staging wave-private, pitch 40, <=1271) ----

    // q^T via A-slice scratch, two 32-token passes [32][40]
    hfx8 qf[4];
    {
        float b0 = bb[w * 32 + c], b1 = bb[w * 32 + 16 + c];
#pragma unroll
        for (int th = 0; th < 2; th++) {
#pragma unroll
            for (int m2 = 0; m2 < 2; m2++)
#pragma unroll
                for (int j = 0; j < 4; j++) {
                    S[(m2 * 16 + g * 4 + j) * 40 + c]      = f2h(qa[th * 2 + m2][0][j] + b0);
                    S[(m2 * 16 + g * 4 + j) * 40 + 16 + c] = f2h(qa[th * 2 + m2][1][j] + b1);
                }
            LGKM0();
#pragma unroll
            for (int np = 0; np < 2; np++)
                qf[th * 2 + np] = *reinterpret_cast<const hfx8*>(S + (np * 16 + c) * 40 + g * 8);
            LGKM0();
        }
    }

    // k^T
    hfx8 kf[4];
    {
        float b0 = bb[256 + w * 32 + c], b1 = bb[256 + w * 32 + 16 + c];
#pragma unroll
        for (int th = 0; th < 2; th++) {
#pragma unroll
            for (int m2 = 0; m2 < 2; m2++)
#pragma unroll
                for (int j = 0; j < 4; j++) {
                    S[(m2 * 16 + g * 4 + j) * 40 + c]      = f2h(ka[th * 2 + m2][0][j] + b0);
                    S[(m2 * 16 + g * 4 + j) * 40 + 16 + c] = f2h(ka[th * 2 + m2][1][j] + b1);
                }
            LGKM0();
#pragma unroll
            for (int np = 0; np < 2; np++)
                kf[th * 2 + np] = *reinterpret_cast<const hfx8*>(S + (np * 16 + c) * 40 + g * 8);
            LGKM0();
        }
    }

    // QK^T in S^T orientation: sa[m][np] = S^T[key 16m+4g+j][token 16np+c]
    f32x4 sa[4][4] = {};
    __builtin_amdgcn_s_setprio(1);
#pragma unroll
    for (int m = 0; m < 4; m++)
#pragma unroll
        for (int np = 0; np < 4; np++)
            sa[m][np] = MFMA16(kf[m], qf[np], sa[m][np]);
    __builtin_amdgcn_s_setprio(0);

    // softmax over keys (rows of S^T)
    float rs[4];
#pragma unroll
    for (int np = 0; np < 4; np++) {
        float mx = sa[0][np][0];
#pragma unroll
        for (int m = 0; m < 4; m++)
#pragma unroll
            for (int j = 0; j < 4; j++) mx = fmaxf(mx, sa[m][np][j]);
        mx = fmaxf(mx, __shfl_xor(mx, 16));
        mx = fmaxf(mx, __shfl_xor(mx, 32));
        float sum = 0.f;
#pragma unroll
        for (int m = 0; m < 4; m++)
#pragma unroll
            for (int j = 0; j < 4; j++) {
                float e = __expf(sa[m][np][j] - mx);
                sa[m][np][j] = e;
                sum += e;
            }
        sum += __shfl_xor(sum, 16);
        sum += __shfl_xor(sum, 32);
        rs[np] = 1.0f / sum;
    }

    // pack P^T to f16 pairs in registers
    unsigned Pp[4][4][2];
#pragma unroll
    for (int m = 0; m < 4; m++)
#pragma unroll
        for (int np = 0; np < 4; np++) {
            Pp[m][np][0] = pk2h(sa[m][np][0], sa[m][np][1]);
            Pp[m][np][1] = pk2h(sa[m][np][2], sa[m][np][3]);
        }

    // vGEMM from xo (xs_hat slots of all waves); v half-panel prefetched
    f32x4 va[4][2] = {};
    {
        __builtin_amdgcn_s_setprio(1);
#pragma unroll
        for (int ks = 0; ks < 8; ks++) {
            hfx8 af[4];
#pragma unroll
            for (int m = 0; m < 4; m++)
                af[m] = *reinterpret_cast<const hfx8*>(xo[ks] + xoidx(m * 16 + c, g * 8));
            hfx8 v1 = *reinterpret_cast<const hfx8*>(wv1 + ks * 32);
#pragma unroll
            for (int m = 0; m < 4; m++) {
                va[m][0] = MFMA16(af[m], vw0[ks], va[m][0]);
                va[m][1] = MFMA16(af[m], v1, va[m][1]);
            }
        }
        __builtin_amdgcn_s_setprio(0);
    }

    // prefetch proj half-panel: latency hides under V^T + PV
    hfx8 pw0[8];
#pragma unroll
    for (int ks = 0; ks < 8; ks++)
        pw0[ks] = *reinterpret_cast<const hfx8*>(wp0 + ks * 32);

    // V^T through A-slice scratch in TWO key-half passes [32 d][32 keys] pitch 40
    hfx8 vf[2][2];
    {
        float b0 = bb[512 + w * 32 + c], b1 = bb[512 + w * 32 + 16 + c];
#pragma unroll
        for (int ks = 0; ks < 2; ks++) {
#pragma unroll
            for (int m2 = 0; m2 < 2; m2++) {
                int m = ks * 2 + m2;
                bfx4 t0, t1;
#pragma unroll
                for (int j = 0; j < 4; j++) {
                    t0[j] = f2h(va[m][0][j] + b0);
                    t1[j] = f2h(va[m][1][j] + b1);
                }
                *reinterpret_cast<bfx4*>(S + c * 40 + m2 * 16 + g * 4)        = t0;
                *reinterpret_cast<bfx4*>(S + (16 + c) * 40 + m2 * 16 + g * 4) = t1;
            }
            LGKM0();
#pragma unroll
            for (int mD = 0; mD < 2; mD++)
                vf[ks][mD] = *reinterpret_cast<const hfx8*>(S + (mD * 16 + c) * 40 + g * 8);
            LGKM0();
        }
    }

    // PV: O^T accumulate; P^T through A-slice [32][40] in 4 rounds (key-half x token-half)
    f32x4 oa[2][4] = {};
#pragma unroll
    for (int ks = 0; ks < 2; ks++) {
#pragma unroll
        for (int th = 0; th < 2; th++) {
#pragma unroll
            for (int m2 = 0; m2 < 2; m2++)
#pragma unroll
                for (int np = 0; np < 2; np++) {
                    *reinterpret_cast<unsigned*>(S + (np * 16 + c) * 40 + m2 * 16 + g * 4)     = Pp[ks * 2 + m2][th * 2 + np][0];
                    *reinterpret_cast<unsigned*>(S + (np * 16 + c) * 40 + m2 * 16 + g * 4 + 2) = Pp[ks * 2 + m2][th * 2 + np][1];
                }
            LGKM0();
            hfx8 pf[2];
#pragma unroll
            for (int np = 0; np < 2; np++)
                pf[np] = *reinterpret_cast<const hfx8*>(S + (np * 16 + c) * 40 + g * 8);
            LGKM0();
            __builtin_amdgcn_s_setprio(1);
#pragma unroll
            for (int mD = 0; mD < 2; mD++)
#pragma unroll
                for (int np = 0; np < 2; np++)
                    oa[mD][th * 2 + np] = MFMA16(vf[ks][mD], pf[np], oa[mD][th * 2 + np]);
            __builtin_amdgcn_s_setprio(0);
        }
    }
    __syncthreads();  // bar2: all xs_hat reads (vGEMM) done -> xo reusable as o_s

    // o_s (normalized) -> xo[w]
#pragma unroll
    for (int mD = 0; mD < 2; mD++)
#pragma unroll
        for (int np = 0; np < 4; np++) {
            bfx4 o4;
#pragma unroll
            for (int j = 0; j < 4; j++) o4[j] = f2h(oa[mD][np][j] * rs[np]);
            *reinterpret_cast<bfx4*>(xo[w] + xoidx(np * 16 + c, mD * 16 + g * 4)) = o4;
        }
    __syncthreads();  // bar3: o_s ready

    // proj (wave = 32 output channels) + direct C-layout fp32 stores
    {
        f32x4 pa[4][2] = {};
        __builtin_amdgcn_s_setprio(1);
#pragma unroll
        for (int ks = 0; ks < 8; ks++) {
            hfx8 af[4];
#pragma unroll
            for (int m = 0; m < 4; m++)
                af[m] = *reinterpret_cast<const hfx8*>(xo[ks] + xoidx(m * 16 + c, g * 8));
            hfx8 p1 = *reinterpret_cast<const hfx8*>(wp1 + ks * 32);
#pragma unroll
            for (int m = 0; m < 4; m++) {
                pa[m][0] = MFMA16(af[m], pw0[ks], pa[m][0]);
                pa[m][1] = MFMA16(af[m], p1, pa[m][1]);
            }
        }
        __builtin_amdgcn_s_setprio(0);
        float* outb = out + (size_t)b * 1048576 + ch * 64;
#pragma unroll
        for (int p = 0; p < 2; p++) {
            int co = w * 32 + p * 16 + c;
            float bvv = bb[768 + co];
            float* op = outb + (size_t)co * 4096 + g * 4;
#pragma unroll
            for (int m = 0; m < 4; m++) {
                float4 st;
                st.x = pa[m][p][0] + bvv;
                st.y = pa[m][p][1] + bvv;
                st.z = pa[m][p][2] + bvv;
                st.w = pa[m][p][3] + bvv;
                *reinterpret_cast<float4*>(op + m * 16) = st;
            }
        }
    }
}

extern "C" void kernel_launch(void* const* d_in, const int* in_sizes, int n_in,
                              void* d_out, int out_size, void* d_ws, size_t ws_size,
                              hipStream_t stream) {
    const float* x   = (const float*)d_in[0];
    const float* cva = (const float*)d_in[1];
    const float* qg  = (const float*)d_in[2];
    const float* qb  = (const float*)d_in[3];
    const float* kg  = (const float*)d_in[4];
    const float* kb  = (const float*)d_in[5];
    const float* vg  = (const float*)d_in[6];
    const float* vb  = (const float*)d_in[7];
    const float* Wq  = (const float*)d_in[8];
    const float* bq  = (const float*)d_in[9];
    const float* Wk  = (const float*)d_in[10];
    const float* bk  = (const float*)d_in[11];
    const float* Wv  = (const float*)d_in[12];
    const float* bv  = (const float*)d_in[13];
    const float* Wp  = (const float*)d_in[14];
    const float* bp  = (const float*)d_in[15];
    float* out = (float*)d_out;
    char* ws = (char*)d_ws;

    short* wt  = (short*)(ws);
    float* bb  = (float*)(ws + 4 * 65536 * sizeof(short));
    float* bbp = bb + 1024;

    prep_w<<<dim3(4, 16), 256, 0, stream>>>(Wq, Wk, Wv, Wp, qg, qb, kg, kb, vg, vb,
                                            wt, bbp);
    prep_b<<<4, 256, 0, stream>>>(bq, bk, bv, bp, bbp, bb);

    mega<<<512, 512, 0, stream>>>(x, cva, wt, bb, out);
}

// Round 14
// 67.580 us; speedup vs baseline: 1.1634x; 1.1090x over previous
//
#include <hip/hip_runtime.h>
#include <hip/hip_bf16.h>

#define NTOK 4096
#define BATCH 8
#define NROWS (BATCH * NTOK)   // 32768

typedef __attribute__((ext_vector_type(8))) _Float16 hfx8;
typedef __attribute__((ext_vector_type(4))) _Float16 hfx4;
typedef __attribute__((ext_vector_type(4))) float f32x4;

// float -> f16 bits (RTE via _Float16 cast)
__device__ __forceinline__ short f2h(float f) {
    _Float16 h = (_Float16)f;
    return __builtin_bit_cast(short, h);
}

// XOR swizzle for the shared A[64][256] tile (8-short granular, bijective per row)
__device__ __forceinline__ int aswz(int row, int col) {
    return (row * 256 + col) ^ ((row & 7) << 3);
}
// unit-rotation swizzle for per-wave xo[64][32] slots: 2-way-free column reads
__device__ __forceinline__ int xoidx(int row, int col) {
    return row * 32 + ((((col >> 3) + (row >> 1)) & 3) << 3) + (col & 7);
}

#define MFMA32(a, b, c) __builtin_amdgcn_mfma_f32_16x16x32_f16(a, b, c, 0, 0, 0)
#define MFMA16(a, b, c) __builtin_amdgcn_mfma_f32_16x16x16f16(a, b, c, 0, 0, 0)

// ---------------- weight prep: WT[co][ci] = f16(scale * g[ci] * W[ci][co]) ----------------
__global__ __launch_bounds__(256) void prep_w(
    const float* __restrict__ Wq, const float* __restrict__ Wk,
    const float* __restrict__ Wv, const float* __restrict__ Wp,
    const float* __restrict__ qg, const float* __restrict__ qb,
    const float* __restrict__ kg, const float* __restrict__ kb,
    const float* __restrict__ vg, const float* __restrict__ vb,
    short* __restrict__ wt, float* __restrict__ bbp) {
    int m = blockIdx.x;
    int ci0 = blockIdx.y * 16;
    const float *W, *g, *be;
    float scale = 1.0f;
    if (m == 0)      { W = Wq; g = qg; be = qb; scale = 0.17677669529663687f; }
    else if (m == 1) { W = Wk; g = kg; be = kb; }
    else if (m == 2) { W = Wv; g = vg; be = vb; }
    else             { W = Wp; g = nullptr; be = nullptr; }
    __shared__ float tile[16][257];
    int t = threadIdx.x;
#pragma unroll
    for (int i = 0; i < 16; i++)
        tile[i][t] = W[(size_t)(ci0 + i) * 256 + t];
    __syncthreads();
    float p = 0.f;
    if (be) {
#pragma unroll
        for (int i = 0; i < 16; i++) p += be[ci0 + i] * tile[i][t];
    }
    bbp[(m * 16 + blockIdx.y) * 256 + t] = p;
    short* WT = wt + m * 65536 + t * 256 + ci0;
    short o0[8], o1[8];
#pragma unroll
    for (int j = 0; j < 8; j++) {
        float gv = g ? g[ci0 + j] : 1.0f;
        o0[j] = f2h(scale * gv * tile[j][t]);
    }
#pragma unroll
    for (int j = 0; j < 8; j++) {
        float gv = g ? g[ci0 + 8 + j] : 1.0f;
        o1[j] = f2h(scale * gv * tile[8 + j][t]);
    }
#pragma unroll
    for (int j = 0; j < 8; j++) { WT[j] = o0[j]; WT[8 + j] = o1[j]; }
}

__global__ __launch_bounds__(256) void prep_b(
    const float* __restrict__ bq, const float* __restrict__ bk,
    const float* __restrict__ bv, const float* __restrict__ bp,
    const float* __restrict__ bbp, float* __restrict__ bb) {
    int m = blockIdx.x, t = threadIdx.x;
    const float* bias = (m == 0) ? bq : (m == 1) ? bk : (m == 2) ? bv : bp;
    float scale = (m == 0) ? 0.17677669529663687f : 1.0f;
    float s = bias[t];
#pragma unroll
    for (int i = 0; i < 16; i++) s += bbp[(m * 16 + i) * 256 + t];
    bb[m * 256 + t] = scale * s;
}

// ---------------- mega kernel: LN + qkv GEMM + attention + projection ----------------
// 512 blocks (b, chunk) x 512 threads (8 waves; wave = head = 32-col strip).
// ZERO LDS transposes: q,k computed pre-transposed via MFMA operand swap
// (MFMA(w_frag, af) -> q^T in C-layout); QK^T and PV run register-only using
// K=16 mfma_f32_16x16x16f16 (C-layout tile == A/B fragment of its transpose).
// A (swizzled [64][256]): cva_hat -> (dead) -> o_s.   xo: xs_hat (permanent).
// 3 barriers, no inline asm.
__global__ __launch_bounds__(512, 4) void mega(const float* __restrict__ x,
                                               const float* __restrict__ cva,
                                               const short* __restrict__ wt,
                                               const float* __restrict__ bb,
                                               float* __restrict__ out) {
    int id = blockIdx.x;
    int b = id >> 6, ch = id & 63;
    int t = threadIdx.x, w = t >> 6, l = t & 63, c = l & 15, g = l >> 4;

    __shared__ short A[64 * 256];       // 32768 B
    __shared__ short xo[8][2048];       // 32768 B
    __shared__ float red[8][64][2];     // 4096 B

    const float* xb   = x + (size_t)b * 1048576 + ch * 64;
    const float* cvab = cva + (size_t)(b * 4096 + ch * 64) * 256;

    // ph0: cva loads -> LN -> A;  x loads -> stats partials -> red -> xs_hat -> xo
    {
        int r16 = g;  // row within pass-quad (16 lanes per row)
        float fv[2][16];
#pragma unroll
        for (int p2 = 0; p2 < 2; p2++) {
            int row = w * 8 + p2 * 4 + r16;
#pragma unroll
            for (int i = 0; i < 4; i++) {
                float4 v4 = *reinterpret_cast<const float4*>(
                    cvab + (size_t)row * 256 + c * 16 + i * 4);
                fv[p2][i * 4 + 0] = v4.x;
                fv[p2][i * 4 + 1] = v4.y;
                fv[p2][i * 4 + 2] = v4.z;
                fv[p2][i * 4 + 3] = v4.w;
            }
        }
        // issue x column loads early (latency hidden under LN compute)
        float xg[32];
#pragma unroll
        for (int i = 0; i < 32; i++) xg[i] = xb[(size_t)(w * 32 + i) * 4096 + l];

#pragma unroll
        for (int p2 = 0; p2 < 2; p2++) {
            int row = w * 8 + p2 * 4 + r16;
            float s = 0.f, q2 = 0.f;
#pragma unroll
            for (int i = 0; i < 16; i++) {
                s += fv[p2][i];
                q2 += fv[p2][i] * fv[p2][i];
            }
            s += __shfl_xor(s, 1);  q2 += __shfl_xor(q2, 1);
            s += __shfl_xor(s, 2);  q2 += __shfl_xor(q2, 2);
            s += __shfl_xor(s, 4);  q2 += __shfl_xor(q2, 4);
            s += __shfl_xor(s, 8);  q2 += __shfl_xor(q2, 8);
            float mean = s * (1.0f / 256.0f);
            float rstd = rsqrtf(q2 * (1.0f / 256.0f) - mean * mean + 1e-5f);
            short o0[8], o1[8];
#pragma unroll
            for (int jj = 0; jj < 8; jj++) {
                o0[jj] = f2h((fv[p2][jj] - mean) * rstd);
                o1[jj] = f2h((fv[p2][8 + jj] - mean) * rstd);
            }
            short* d0 = A + aswz(row, c * 16);
            short* d1 = A + aswz(row, c * 16 + 8);
#pragma unroll
            for (int jj = 0; jj < 8; jj++) { d0[jj] = o0[jj]; d1[jj] = o1[jj]; }
        }

        // x stats partials (token = l, c-slice = w*32..+32)
        float s = 0.f, q2 = 0.f;
#pragma unroll
        for (int i = 0; i < 32; i++) { s += xg[i]; q2 += xg[i] * xg[i]; }
        red[w][l][0] = s;
        red[w][l][1] = q2;
        __syncthreads();  // bar0: cva_hat ready, red ready

        // xs_hat -> xo[w] (rot-swizzled [64][32])
        float s2 = 0.f, q22 = 0.f;
#pragma unroll
        for (int j2 = 0; j2 < 8; j2++) { s2 += red[j2][l][0]; q22 += red[j2][l][1]; }
        float xmean = s2 * (1.0f / 256.0f);
        float xrstd = rsqrtf(q22 * (1.0f / 256.0f) - xmean * xmean + 1e-5f);
#pragma unroll
        for (int i2 = 0; i2 < 4; i2++) {
            short* dd = xo[w] + xoidx(l, i2 * 8);
#pragma unroll
            for (int jj = 0; jj < 8; jj++) dd[jj] = f2h((xg[i2 * 8 + jj] - xmean) * xrstd);
        }
    }

    // ph1: q^T,k^T GEMM via operand swap: D = MFMA(w_frag, af) -> [d][tok] C-layout.
    // qa[mt][nt]: lane (c,g) reg j = q^T[d = w*32+16mt+4g+j][tok = 16nt+c]
    f32x4 qa[2][4] = {}, ka[2][4] = {};
    {
        const short* wq0 = wt + (size_t)(w * 32 + c) * 256 + g * 8;
        const short* wq1 = wq0 + 16 * 256;
        const short* wk0 = wq0 + 65536;
        const short* wk1 = wq1 + 65536;
#pragma unroll
        for (int ks = 0; ks < 8; ks++) {
            hfx8 af[4];
#pragma unroll
            for (int nt = 0; nt < 4; nt++)
                af[nt] = *reinterpret_cast<const hfx8*>(A + aswz(nt * 16 + c, ks * 32 + g * 8));
            hfx8 q0 = *reinterpret_cast<const hfx8*>(wq0 + ks * 32);
            hfx8 q1 = *reinterpret_cast<const hfx8*>(wq1 + ks * 32);
            hfx8 k0 = *reinterpret_cast<const hfx8*>(wk0 + ks * 32);
            hfx8 k1 = *reinterpret_cast<const hfx8*>(wk1 + ks * 32);
#pragma unroll
            for (int nt = 0; nt < 4; nt++) {
                qa[0][nt] = MFMA32(q0, af[nt], qa[0][nt]);
                qa[1][nt] = MFMA32(q1, af[nt], qa[1][nt]);
                ka[0][nt] = MFMA32(k0, af[nt], ka[0][nt]);
                ka[1][nt] = MFMA32(k1, af[nt], ka[1][nt]);
            }
        }
    }
    __syncthreads();  // bar1: all cva_hat reads done -> A reusable for o_s

    // bias + f16 convert, in registers (C-layout tile == K=16 fragment of transpose)
    hfx4 qTf[2][4], kTf[2][4];
#pragma unroll
    for (int mt = 0; mt < 2; mt++) {
        f32x4 bq4 = *reinterpret_cast<const f32x4*>(bb + w * 32 + mt * 16 + g * 4);
        f32x4 bk4 = *reinterpret_cast<const f32x4*>(bb + 256 + w * 32 + mt * 16 + g * 4);
#pragma unroll
        for (int nt = 0; nt < 4; nt++)
#pragma unroll
            for (int j = 0; j < 4; j++) {
                qTf[mt][nt][j] = (_Float16)(qa[mt][nt][j] + bq4[j]);
                kTf[mt][nt][j] = (_Float16)(ka[mt][nt][j] + bk4[j]);
            }
    }

    // QK^T register-only: saT[ntk][ntq] lane (c,g) reg j = S^T[key=16ntk+4g+j][tok=16ntq+c]
    f32x4 saT[4][4] = {};
#pragma unroll
    for (int mt = 0; mt < 2; mt++)
#pragma unroll
        for (int ntk = 0; ntk < 4; ntk++)
#pragma unroll
            for (int ntq = 0; ntq < 4; ntq++)
                saT[ntk][ntq] = MFMA16(kTf[mt][ntk], qTf[mt][ntq], saT[ntk][ntq]);

    // softmax over keys (in-lane ntk,j + shfl 16/32 over g)
    float rs[4];
#pragma unroll
    for (int ntq = 0; ntq < 4; ntq++) {
        float mx = saT[0][ntq][0];
#pragma unroll
        for (int ntk = 0; ntk < 4; ntk++)
#pragma unroll
            for (int j = 0; j < 4; j++) mx = fmaxf(mx, saT[ntk][ntq][j]);
        mx = fmaxf(mx, __shfl_xor(mx, 16));
        mx = fmaxf(mx, __shfl_xor(mx, 32));
        float sum = 0.f;
#pragma unroll
        for (int ntk = 0; ntk < 4; ntk++)
#pragma unroll
            for (int j = 0; j < 4; j++) {
                float e = __expf(saT[ntk][ntq][j] - mx);
                saT[ntk][ntq][j] = e;
                sum += e;
            }
        sum += __shfl_xor(sum, 16);
        sum += __shfl_xor(sum, 32);
        rs[ntq] = 1.0f / sum;
    }

    // normalized P pack, register-only: Pf[ks][mo] = P[tok=16mo+c][key=16ks+4g+j]
    hfx4 Pf[4][4];
#pragma unroll
    for (int ks = 0; ks < 4; ks++)
#pragma unroll
        for (int mo = 0; mo < 4; mo++)
#pragma unroll
            for (int j = 0; j < 4; j++)
                Pf[ks][mo][j] = (_Float16)(saT[ks][mo][j] * rs[mo]);

    // vGEMM (normal orientation): va[m][n] lane reg j = v[key=16m+4g+j][d=16n+c]
    f32x4 va[4][2] = {};
    {
        const short* wv0 = wt + 2 * 65536 + (size_t)(w * 32 + c) * 256 + g * 8;
        const short* wv1 = wv0 + 16 * 256;
#pragma unroll
        for (int ks = 0; ks < 8; ks++) {
            hfx8 af[4];
#pragma unroll
            for (int m = 0; m < 4; m++)
                af[m] = *reinterpret_cast<const hfx8*>(xo[ks] + xoidx(m * 16 + c, g * 8));
            hfx8 v0 = *reinterpret_cast<const hfx8*>(wv0 + ks * 32);
            hfx8 v1 = *reinterpret_cast<const hfx8*>(wv1 + ks * 32);
#pragma unroll
            for (int m = 0; m < 4; m++) {
                va[m][0] = MFMA32(af[m], v0, va[m][0]);
                va[m][1] = MFMA32(af[m], v1, va[m][1]);
            }
        }
    }

    // v bias + f16 convert in registers (C-layout == K=16 B-fragment)
    hfx4 vf[4][2];
    {
        float bv0 = bb[512 + w * 32 + c], bv1 = bb[512 + w * 32 + 16 + c];
#pragma unroll
        for (int m = 0; m < 4; m++)
#pragma unroll
            for (int j = 0; j < 4; j++) {
                vf[m][0][j] = (_Float16)(va[m][0][j] + bv0);
                vf[m][1][j] = (_Float16)(va[m][1][j] + bv1);
            }
    }

    // PV register-only: oacc[mo][no] lane reg j = O[tok=16mo+4g+j][d=16no+c]
    f32x4 oacc[4][2] = {};
#pragma unroll
    for (int ks = 0; ks < 4; ks++)
#pragma unroll
        for (int mo = 0; mo < 4; mo++)
#pragma unroll
            for (int no = 0; no < 2; no++)
                oacc[mo][no] = MFMA16(Pf[ks][mo], vf[ks][no], oacc[mo][no]);

    // o_s -> A (rows = tok, cols = ch); P pre-normalized so no scale here
#pragma unroll
    for (int mo = 0; mo < 4; mo++)
#pragma unroll
        for (int no = 0; no < 2; no++)
#pragma unroll
            for (int j = 0; j < 4; j++)
                A[aswz(mo * 16 + 4 * g + j, w * 32 + no * 16 + c)] = f2h(oacc[mo][no][j]);
    __syncthreads();  // bar2: o_s ready

    // proj (wave = 32 output channels) + direct C-layout fp32 stores
    {
        f32x4 pa[4][2] = {};
        const short* wp0 = wt + 3 * 65536 + (size_t)(w * 32 + c) * 256 + g * 8;
        const short* wp1 = wp0 + 16 * 256;
#pragma unroll
        for (int ks = 0; ks < 8; ks++) {
            hfx8 af[4];
#pragma unroll
            for (int m = 0; m < 4; m++)
                af[m] = *reinterpret_cast<const hfx8*>(A + aswz(m * 16 + c, ks * 32 + g * 8));
            hfx8 p0 = *reinterpret_cast<const hfx8*>(wp0 + ks * 32);
            hfx8 p1 = *reinterpret_cast<const hfx8*>(wp1 + ks * 32);
#pragma unroll
            for (int m = 0; m < 4; m++) {
                pa[m][0] = MFMA32(af[m], p0, pa[m][0]);
                pa[m][1] = MFMA32(af[m], p1, pa[m][1]);
            }
        }
        float* outb = out + (size_t)b * 1048576 + ch * 64;
#pragma unroll
        for (int p = 0; p < 2; p++) {
            int co = w * 32 + p * 16 + c;
            float bvv = bb[768 + co];
            float* op = outb + (size_t)co * 4096 + g * 4;
#pragma unroll
            for (int m = 0; m < 4; m++) {
                float4 st;
                st.x = pa[m][p][0] + bvv;
                st.y = pa[m][p][1] + bvv;
                st.z = pa[m][p][2] + bvv;
                st.w = pa[m][p][3] + bvv;
                *reinterpret_cast<float4*>(op + m * 16) = st;
            }
        }
    }
}

extern "C" void kernel_launch(void* const* d_in, const int* in_sizes, int n_in,
                              void* d_out, int out_size, void* d_ws, size_t ws_size,
                              hipStream_t stream) {
    const float* x   = (const float*)d_in[0];
    const float* cva = (const float*)d_in[1];
    const float* qg  = (const float*)d_in[2];
    const float* qb  = (const float*)d_in[3];
    const float* kg  = (const float*)d_in[4];
    const float* kb  = (const float*)d_in[5];
    const float* vg  = (const float*)d_in[6];
    const float* vb  = (const float*)d_in[7];
    const float* Wq  = (const float*)d_in[8];
    const float* bq  = (const float*)d_in[9];
    const float* Wk  = (const float*)d_in[10];
    const float* bk  = (const float*)d_in[11];
    const float* Wv  = (const float*)d_in[12];
    const float* bv  = (const float*)d_in[13];
    const float* Wp  = (const float*)d_in[14];
    const float* bp  = (const float*)d_in[15];
    float* out = (float*)d_out;
    char* ws = (char*)d_ws;

    short* wt  = (short*)(ws);
    float* bb  = (float*)(ws + 4 * 65536 * sizeof(short));
    float* bbp = bb + 1024;

    prep_w<<<dim3(4, 16), 256, 0, stream>>>(Wq, Wk, Wv, Wp, qg, qb, kg, kb, vg, vb,
                                            wt, bbp);
    prep_b<<<4, 256, 0, stream>>>(bq, bk, bv, bp, bbp, bb);

    mega<<<512, 512, 0, stream>>>(x, cva, wt, bb, out);
}